// Round 14
// baseline (276.905 us; speedup 1.0000x reference)
//
#include <hip/hip_runtime.h>
#include <hip/hip_bf16.h>
#include <math.h>

#define N_ROWS 65536
#define P_DIM  256
#define C_DIM  3
#define U_DIM  512

#define BM 64
#define BU 128
#define NUT (U_DIM / BU)               // 4 u-tiles, persistent per block
#define NPL 4                          // B planes: K, var1*K^2, var2*K^2, var3*K^2
#define NACC 6                         // 3 mean accs + 3 var accs

typedef __attribute__((ext_vector_type(8))) short short8;     // 8 bf16 = 4 VGPR
typedef __attribute__((ext_vector_type(4))) float f32x4;
typedef __attribute__((ext_vector_type(4))) float floatx4;
typedef __attribute__((ext_vector_type(4))) unsigned int uint4v;

static __device__ __forceinline__ unsigned short f2bf(float f) {
    unsigned int u = __builtin_bit_cast(unsigned int, f);
    u += 0x7FFFu + ((u >> 16) & 1u);      // RNE
    return (unsigned short)(u >> 16);
}

// E[relu(N(m, v))]; exact relu when v == 0.
// Single-instruction rsq/rcp (1 ulp), Phi via Zelen-Severo poly reusing g = phi(w).
static __device__ __forceinline__ float erl(float m, float v) {
    float r = __builtin_amdgcn_rsqf(fmaxf(v, 1e-20f));
    float w = m * r;
    float s = v * r;
    float g = __expf(-0.5f * w * w) * 0.3989422804014327f;       // phi(w), even in w
    float aw = fabsf(w);
    float t = __builtin_amdgcn_rcpf(fmaf(0.2316419f, aw, 1.0f));
    float poly = t * (0.319381530f + t * (-0.356563782f + t * (1.781477937f
               + t * (-1.821255978f + t * 1.330274429f))));
    float Phi_pos = 1.0f - g * poly;
    float phi = (w >= 0.0f) ? Phi_pos : 1.0f - Phi_pos;
    float val = s * g + m * phi;
    return (v > 0.0f) ? val : fmaxf(m, 0.0f);
}

// ---------------- prep: fragment-packed B (4 planes) + q-tables ----------------
// Bf[ut][wc][ks][pl][lane][e], contiguous 1KB per wave-fragment.
//   u = ut*128 + wc*16 + (lane&15);  k = ks*32 + (lane>>4)*8 + e
//   pl0: kernel[k][u]; pl 1..3: var_c[k] * kernel[k][u]^2
// qtab[p] = 3 float4 (a,b,d per component): q_c(x) = (a x + b) x + d
__global__ __launch_bounds__(512) void prep_kernel(
    const float* __restrict__ cmeans, const float* __restrict__ cvars,
    const float* __restrict__ kern, unsigned short* __restrict__ Bf,
    float* __restrict__ qtab)
{
    int tid = blockIdx.x * 512 + threadIdx.x;
    const int TOTAL_B = NUT * 8 * 8 * NPL * 64 * 8;   // 524288
    if (tid < TOTAL_B) {
        int e    = tid & 7;
        int lane = (tid >> 3) & 63;
        int rest = tid >> 9;          // 0..1023
        int pl   = rest & 3;
        int ks   = (rest >> 2) & 7;
        int wc   = (rest >> 5) & 7;
        int ut   = rest >> 8;
        int u = ut * BU + wc * 16 + (lane & 15);
        int k = ks * 32 + (lane >> 4) * 8 + e;
        float kv = kern[k * U_DIM + u];
        float val = (pl == 0) ? kv : cvars[k * C_DIM + (pl - 1)] * (kv * kv);
        Bf[tid] = f2bf(val);
    } else if (tid - TOTAL_B < P_DIM) {
        int p = tid - TOTAL_B;
        float a[3], b[3], d[3];
#pragma unroll
        for (int c = 0; c < 3; ++c) {
            float m = cmeans[p * 3 + c];
            float v = cvars[p * 3 + c];
            float iv = 0.5f / v;
            a[c] = iv;
            b[c] = -2.0f * m * iv;
            d[c] = m * m * iv + 0.5f * logf(2.0f * 3.14159265359f * v);
        }
        float* q = qtab + p * 12;
        q[0] = a[0]; q[1] = a[1]; q[2]  = a[2]; q[3]  = 0.f;
        q[4] = b[0]; q[5] = b[1]; q[6]  = b[2]; q[7]  = 0.f;
        q[8] = d[0]; q[9] = d[1]; q[10] = d[2]; q[11] = 0.f;
    }
}

// load 4 B-plane fragments for k-step ksi into slot regs (coalesced 1KB blocks)
#define LOADB(dst, ksi) do {                                                  \
    _Pragma("unroll")                                                         \
    for (int pl = 0; pl < NPL; ++pl)                                          \
        dst[pl] = *(const short8*)(bpw + ((ksi) * NPL + pl) * 512);           \
} while (0)

// one k-step: 8 conflict-free LDS A-reads + 12 MFMAs using B slot `breg`
// LDS plane layout: elem = rowblk*4096 + ks*512 + lk*128 + r16*8 ; rowblk = wr*2+r
#define STEP(breg, ksi) do {                                                  \
    __builtin_amdgcn_s_setprio(1);                                            \
    _Pragma("unroll")                                                         \
    for (int r = 0; r < 2; ++r) {                                             \
        int _ao = aBase + r * 4096 + (ksi) * 512;                             \
        short8 a1 = *(const short8*)&lA1[_ao];                                \
        short8 a2 = *(const short8*)&lA2[_ao];                                \
        short8 a3 = *(const short8*)&lA3[_ao];                                \
        short8 am = *(const short8*)&lMK[_ao];                                \
        acc[0][r] = __builtin_amdgcn_mfma_f32_16x16x32_bf16(a1, breg[0], acc[0][r], 0, 0, 0); \
        acc[1][r] = __builtin_amdgcn_mfma_f32_16x16x32_bf16(a2, breg[0], acc[1][r], 0, 0, 0); \
        acc[2][r] = __builtin_amdgcn_mfma_f32_16x16x32_bf16(a3, breg[0], acc[2][r], 0, 0, 0); \
        acc[3][r] = __builtin_amdgcn_mfma_f32_16x16x32_bf16(am, breg[1], acc[3][r], 0, 0, 0); \
        acc[4][r] = __builtin_amdgcn_mfma_f32_16x16x32_bf16(am, breg[2], acc[4][r], 0, 0, 0); \
        acc[5][r] = __builtin_amdgcn_mfma_f32_16x16x32_bf16(am, breg[3], acc[5][r], 0, 0, 0); \
    }                                                                         \
    __builtin_amdgcn_s_setprio(0);                                            \
} while (0)

// ---------------- main: A_c = where(nan, mu_c, x) as GEMM A-operand ----------------
// 1024 threads = 16 waves (2 wr x 8 wc), 4 waves/SIMD. Per wave: 32 rows x 16 cols,
// acc[6][2] (48 AGPR). 4-plane packed B with 2-slot ping-pong (32 regs): distance-1
// prefetch AND 4-wave occupancy (48+32+16+addr < 128).
__global__ __launch_bounds__(1024, 4) void main_kernel(
    const float* __restrict__ X, const unsigned short* __restrict__ Bf,
    const float* __restrict__ cmeans, const float* __restrict__ qtab,
    const float* __restrict__ logits, const float* __restrict__ bias,
    float* __restrict__ out)
{
    __shared__ unsigned short lA1[BM * P_DIM];  // where(nan, mu_1, x) bf16 (32 KB)
    __shared__ unsigned short lA2[BM * P_DIM];  // where(nan, mu_2, x)      (32 KB)
    __shared__ unsigned short lA3[BM * P_DIM];  // where(nan, mu_3, x)      (32 KB)
    __shared__ unsigned short lMK[BM * P_DIM];  // mask                     (32 KB)
    __shared__ float pws[BM][3];                // softmax weights          (0.75 KB)

    const int tid = threadIdx.x;
    const int n0 = blockIdx.x * BM;
    const int lane = tid & 63;
    const int wid  = tid >> 6;     // 0..15
    const int l15  = lane & 15;
    const int lk   = lane >> 4;    // 0..3

    // ---- stage: wave quad (wid>>2) owns rowblk; wid&3 owns a ks-pair ----
    {
        const int rowblk = wid >> 2;         // 0..3
        const float* Xb = X + (size_t)(n0 + rowblk * 16 + l15) * P_DIM + lk * 8;
        const int ebase = rowblk * 4096 + lk * 128 + l15 * 8;   // + ks*512
#pragma unroll
        for (int j = 0; j < 2; ++j) {
            int ks = (wid & 3) * 2 + j;
            floatx4 v0 = *(const floatx4*)(Xb + ks * 32);
            floatx4 v1 = *(const floatx4*)(Xb + ks * 32 + 4);
            const float* mup = cmeans + (size_t)(ks * 32 + lk * 8) * 3;  // 24 floats
            floatx4 mA = *(const floatx4*)(mup);
            floatx4 mB = *(const floatx4*)(mup + 4);
            floatx4 mC = *(const floatx4*)(mup + 8);
            floatx4 mD = *(const floatx4*)(mup + 12);
            floatx4 mE = *(const floatx4*)(mup + 16);
            floatx4 mF = *(const floatx4*)(mup + 20);
            float mu[24];
#pragma unroll
            for (int z = 0; z < 4; ++z) {
                mu[z] = mA[z]; mu[4 + z] = mB[z]; mu[8 + z] = mC[z];
                mu[12 + z] = mD[z]; mu[16 + z] = mE[z]; mu[20 + z] = mF[z];
            }
            unsigned int w1[4], w2[4], w3[4], wm[4];
#pragma unroll
            for (int pe = 0; pe < 4; ++pe) {     // pairs of elements
#pragma unroll
                for (int h = 0; h < 2; ++h) {
                    int e = pe * 2 + h;
                    float x = (e < 4) ? v0[e] : v1[e - 4];
                    bool na = !(x == x);
                    unsigned int b1 = (unsigned int)f2bf(na ? mu[e * 3 + 0] : x);
                    unsigned int b2 = (unsigned int)f2bf(na ? mu[e * 3 + 1] : x);
                    unsigned int b3 = (unsigned int)f2bf(na ? mu[e * 3 + 2] : x);
                    unsigned int bm = na ? 0x3F80u : 0u;
                    if (h == 0) { w1[pe] = b1; w2[pe] = b2; w3[pe] = b3; wm[pe] = bm; }
                    else { w1[pe] |= b1 << 16; w2[pe] |= b2 << 16; w3[pe] |= b3 << 16; wm[pe] |= bm << 16; }
                }
            }
            int idx = ebase + ks * 512;
            *(uint4v*)&lA1[idx] = (uint4v){w1[0], w1[1], w1[2], w1[3]};
            *(uint4v*)&lA2[idx] = (uint4v){w2[0], w2[1], w2[2], w2[3]};
            *(uint4v*)&lA3[idx] = (uint4v){w3[0], w3[1], w3[2], w3[3]};
            *(uint4v*)&lMK[idx] = (uint4v){wm[0], wm[1], wm[2], wm[3]};
        }
    }

    // ---- fused loglik + softmax via q-tables: 16 threads per row -> pws[row][3] ----
    {
        int row = tid >> 4;
        int sub = tid & 15;
        const floatx4* xr = (const floatx4*)(X + (size_t)(n0 + row) * P_DIM);
        const floatx4* qt = (const floatx4*)qtab;
        float a0 = 0.f, a1 = 0.f, a2 = 0.f;
#pragma unroll
        for (int i = 0; i < 4; ++i) {
            floatx4 v = xr[sub * 4 + i];
#pragma unroll
            for (int e = 0; e < 4; ++e) {
                float x = v[e];
                int p = sub * 16 + i * 4 + e;
                bool valid = (x == x);
                float xv = valid ? x : 0.f;
                floatx4 qa = qt[p * 3 + 0];
                floatx4 qb = qt[p * 3 + 1];
                floatx4 qd = qt[p * 3 + 2];
                float q0 = fmaf(fmaf(qa[0], xv, qb[0]), xv, qd[0]);
                float q1 = fmaf(fmaf(qa[1], xv, qb[1]), xv, qd[1]);
                float q2 = fmaf(fmaf(qa[2], xv, qb[2]), xv, qd[2]);
                a0 += valid ? q0 : 0.f;
                a1 += valid ? q1 : 0.f;
                a2 += valid ? q2 : 0.f;
            }
        }
#pragma unroll
        for (int off = 1; off < 16; off <<= 1) {
            a0 += __shfl_xor(a0, off);
            a1 += __shfl_xor(a1, off);
            a2 += __shfl_xor(a2, off);
        }
        if (sub == 0) {
            float z0 = logits[0] - a0;
            float z1 = logits[1] - a1;
            float z2 = logits[2] - a2;
            float mx = fmaxf(z0, fmaxf(z1, z2));
            float e0 = __expf(z0 - mx), e1 = __expf(z1 - mx), e2 = __expf(z2 - mx);
            float inv = __builtin_amdgcn_rcpf(e0 + e1 + e2);
            pws[row][0] = e0 * inv;
            pws[row][1] = e1 * inv;
            pws[row][2] = e2 * inv;
        }
    }
    __syncthreads();

    // ---- persistent u-loop: 2-slot ping-pong packed-B k-loop + expected_relu epilogue ----
    const int wr   = wid >> 3;     // 0..1 : 32-row slab
    const int wc   = wid & 7;      // 0..7 : 16-col group
    const int aBase = wr * 8192 + lk * 128 + l15 * 8;     // + r*4096 + ks*512
    const int phase = wc & 3;      // stagger across NUT=4

#pragma unroll 1
    for (int ut0 = 0; ut0 < NUT; ++ut0) {
        const int ut = (ut0 + phase) & (NUT - 1);
        // coalesced fragment base: Bf[ut][wc][.][.][lane][.]
        const unsigned short* bpw = Bf + ((size_t)(ut * 8 + wc) * (8 * NPL * 512)) + (size_t)lane * 8;

        f32x4 acc[NACC][2];
#pragma unroll
        for (int pl = 0; pl < NACC; ++pl)
#pragma unroll
            for (int r = 0; r < 2; ++r)
                acc[pl][r] = (f32x4){0.f, 0.f, 0.f, 0.f};

        short8 bA[NPL], bB[NPL];
        LOADB(bA, 0);
#pragma unroll 1
        for (int ks = 0; ks < 8; ks += 2) {
            LOADB(bB, ks + 1);          // prefetch odd step
            STEP(bA, ks);               // compute even step
            if (ks + 2 < 8) LOADB(bA, ks + 2);   // prefetch next even step
            STEP(bB, ks + 1);           // compute odd step
        }

        // epilogue: D lane map col = lane&15, row = 4*(lane>>4)+q (+ r*16 + wr*32)
        const int ucol = ut * BU + wc * 16 + l15;
        const float bias_u = bias[ucol];
#pragma unroll
        for (int r = 0; r < 2; ++r) {
            int rloc = wr * 32 + r * 16 + 4 * lk;
#pragma unroll
            for (int q = 0; q < 4; ++q) {
                int rl = rloc + q;
                float p0 = pws[rl][0], p1 = pws[rl][1], p2 = pws[rl][2];
                float res = p0 * erl(acc[0][r][q] + bias_u, acc[3][r][q])
                          + p1 * erl(acc[1][r][q] + bias_u, acc[4][r][q])
                          + p2 * erl(acc[2][r][q] + bias_u, acc[5][r][q]);
                out[(size_t)(n0 + rl) * U_DIM + ucol] = res;
            }
        }
    }
}

extern "C" void kernel_launch(void* const* d_in, const int* in_sizes, int n_in,
                              void* d_out, int out_size, void* d_ws, size_t ws_size,
                              hipStream_t stream)
{
    const float* X      = (const float*)d_in[0];
    const float* cmeans = (const float*)d_in[1];
    const float* cvars  = (const float*)d_in[2];
    const float* logits = (const float*)d_in[3];
    const float* kern   = (const float*)d_in[4];
    const float* bias   = (const float*)d_in[5];
    float* out = (float*)d_out;

    char* wsb = (char*)d_ws;
    unsigned short* Bf = (unsigned short*)wsb;                 // 1,048,576 B
    float* qtab = (float*)(wsb + 1048576);                     //    12,288 B

    hipLaunchKernelGGL(prep_kernel, dim3(1025), dim3(512), 0, stream,
                       cmeans, cvars, kern, Bf, qtab);
    hipLaunchKernelGGL(main_kernel, dim3(N_ROWS / BM), dim3(1024), 0, stream,
                       X, Bf, cmeans, qtab, logits, bias, out);
}

// Round 15
// 256.199 us; speedup vs baseline: 1.0808x; 1.0808x over previous
//
#include <hip/hip_runtime.h>
#include <hip/hip_bf16.h>
#include <math.h>

#define N_ROWS 65536
#define P_DIM  256
#define C_DIM  3
#define U_DIM  512
#define NPLANES 7

#define BM 64
#define BU 64
#define NUT (U_DIM / BU)               // 8 u-tiles, persistent per block

typedef __attribute__((ext_vector_type(8))) short short8;     // 8 bf16 = 4 VGPR
typedef __attribute__((ext_vector_type(4))) float f32x4;
typedef __attribute__((ext_vector_type(4))) float floatx4;
typedef __attribute__((ext_vector_type(4))) unsigned int uint4v;

static __device__ __forceinline__ unsigned short f2bf(float f) {
    unsigned int u = __builtin_bit_cast(unsigned int, f);
    u += 0x7FFFu + ((u >> 16) & 1u);      // RNE
    return (unsigned short)(u >> 16);
}

// E[relu(N(m, v))]; exact relu when v == 0.
// Single-instruction rsq/rcp (1 ulp), Phi via Zelen-Severo poly reusing g = phi(w).
static __device__ __forceinline__ float erl(float m, float v) {
    float r = __builtin_amdgcn_rsqf(fmaxf(v, 1e-20f));
    float w = m * r;
    float s = v * r;
    float g = __expf(-0.5f * w * w) * 0.3989422804014327f;       // phi(w), even in w
    float aw = fabsf(w);
    float t = __builtin_amdgcn_rcpf(fmaf(0.2316419f, aw, 1.0f));
    float poly = t * (0.319381530f + t * (-0.356563782f + t * (1.781477937f
               + t * (-1.821255978f + t * 1.330274429f))));
    float Phi_pos = 1.0f - g * poly;
    float phi = (w >= 0.0f) ? Phi_pos : 1.0f - Phi_pos;
    float val = s * g + m * phi;
    return (v > 0.0f) ? val : fmaxf(m, 0.0f);
}

// ---------------- prep: fragment-packed B (7 planes) + q-tables ----------------
// Bf[ut][wc][ks][pl][lane][e]: the exact 1KB a wave reads per (ut,wc,ks,pl) is
// CONTIGUOUS (addr = base + lane*16B) -> 8 cache lines per load inst, not 64.
//   u = ut*64 + wc*16 + (lane&15);  k = ks*32 + (lane>>4)*8 + e
// plane 0: kernel[k][u]; 1+c: mu[k][c]*kernel; 4+c: var[k][c]*kernel^2
// qtab[p] = 3 float4: a_c = 1/(2v), b_c = -2 m a, d_c = m^2 a + 0.5 log(2 pi v)
__global__ __launch_bounds__(512) void prep_kernel(
    const float* __restrict__ cmeans, const float* __restrict__ cvars,
    const float* __restrict__ kern, unsigned short* __restrict__ Bf,
    float* __restrict__ qtab)
{
    int tid = blockIdx.x * 512 + threadIdx.x;
    const int TOTAL_B = NPLANES * U_DIM * P_DIM;   // 917504
    if (tid < TOTAL_B) {
        int e    = tid & 7;
        int lane = (tid >> 3) & 63;
        int rest = tid >> 9;          // 0..1791
        int pl   = rest % 7;
        int rk   = rest / 7;          // 0..255
        int ks   = rk & 7;
        int uw   = rk >> 3;           // 0..31
        int wc   = uw & 3;
        int ut   = uw >> 2;
        int u = ut * 64 + wc * 16 + (lane & 15);
        int k = ks * 32 + (lane >> 4) * 8 + e;
        float kv = kern[k * U_DIM + u];
        float val;
        if (pl == 0)      val = kv;
        else if (pl <= 3) val = cmeans[k * C_DIM + (pl - 1)] * kv;
        else              val = cvars[k * C_DIM + (pl - 4)] * (kv * kv);
        Bf[tid] = f2bf(val);
    } else if (tid - TOTAL_B < P_DIM) {
        int p = tid - TOTAL_B;
        float a[3], b[3], d[3];
#pragma unroll
        for (int c = 0; c < 3; ++c) {
            float m = cmeans[p * 3 + c];
            float v = cvars[p * 3 + c];
            float iv = 0.5f / v;
            a[c] = iv;
            b[c] = -2.0f * m * iv;
            d[c] = m * m * iv + 0.5f * logf(2.0f * 3.14159265359f * v);
        }
        float* q = qtab + p * 12;
        q[0] = a[0]; q[1] = a[1]; q[2]  = a[2]; q[3]  = 0.f;
        q[4] = b[0]; q[5] = b[1]; q[6]  = b[2]; q[7]  = 0.f;
        q[8] = d[0]; q[9] = d[1]; q[10] = d[2]; q[11] = 0.f;
    }
}

// load 7 B-plane fragments for k-step ksi into the single buffer (coalesced 1KB blocks)
#define LOADB(dst, ksi) do {                                                  \
    _Pragma("unroll")                                                         \
    for (int pl = 0; pl < NPLANES; ++pl)                                      \
        dst[pl] = *(const short8*)(bpw + ((ksi) * 7 + pl) * 512);             \
} while (0)

// one k-step: 4 contiguous (conflict-free) LDS A-reads + 14 MFMAs
// fragment-ordered LDS layout: elem = rowblk*4096 + ks*512 + lk*128 + r16*8
#define STEP(breg, ksi) do {                                                  \
    __builtin_amdgcn_s_setprio(1);                                            \
    _Pragma("unroll")                                                         \
    for (int r = 0; r < 2; ++r) {                                             \
        short8 a0 = *(const short8*)&xs[aBase + r * 4096 + (ksi) * 512];      \
        short8 a1 = *(const short8*)&mk[aBase + r * 4096 + (ksi) * 512];      \
        acc[0][r] = __builtin_amdgcn_mfma_f32_16x16x32_bf16(a0, breg[0], acc[0][r], 0, 0, 0); \
        _Pragma("unroll")                                                     \
        for (int pl = 1; pl < NPLANES; ++pl)                                  \
            acc[pl][r] = __builtin_amdgcn_mfma_f32_16x16x32_bf16(a1, breg[pl], acc[pl][r], 0, 0, 0); \
    }                                                                         \
    __builtin_amdgcn_s_setprio(0);                                            \
} while (0)

// ---------------- main: BM=64, 512 threads = 8 waves (2 wr x 4 wc) ----------------
// LDS = 65.5 KB -> TWO independent blocks co-resident per CU (16 waves/CU, 4/SIMD).
// No inter-block barrier: one block's MFMA k-loop overlaps the other's staging /
// erl epilogue, converting the sum-of-phases wall toward max-of-phases.
// Per wave: 32 rows x 16 cols, acc[7][2] (56 AGPR) + single packed-B buffer (28):
// R13's proven no-spill register shape.
__global__ __launch_bounds__(512, 4) void main_kernel(
    const float* __restrict__ X, const unsigned short* __restrict__ Bf,
    const float* __restrict__ qtab, const float* __restrict__ logits,
    const float* __restrict__ bias, float* __restrict__ out)
{
    __shared__ unsigned short xs[BM * P_DIM];   // x_safe bf16, frag-ordered (32 KB)
    __shared__ unsigned short mk[BM * P_DIM];   // mask   bf16, frag-ordered (32 KB)
    __shared__ float pws[BM][3];                // softmax weights           (0.75 KB)

    const int tid = threadIdx.x;
    const int n0 = blockIdx.x * BM;
    const int lane = tid & 63;
    const int wid  = tid >> 6;     // 0..7
    const int l15  = lane & 15;
    const int lk   = lane >> 4;    // 0..3

    // ---- stage x tile: wave pair (wid>>1) owns rowblk (16 rows); wid&1 owns ks-half ----
    {
        const int rowblk = wid >> 1;         // 0..3
        const int ksh    = (wid & 1) * 4;
        const float* Xb = X + (size_t)(n0 + rowblk * 16 + l15) * P_DIM + lk * 8;
        const int ebase = rowblk * 4096 + lk * 128 + l15 * 8;   // + ks*512
#pragma unroll
        for (int j = 0; j < 4; ++j) {
            int ks = ksh + j;
            floatx4 v0 = *(const floatx4*)(Xb + ks * 32);
            floatx4 v1 = *(const floatx4*)(Xb + ks * 32 + 4);
            unsigned int wx[4], wm[4];
#pragma unroll
            for (int h = 0; h < 2; ++h) {
                floatx4 v = h ? v1 : v0;
#pragma unroll
                for (int e = 0; e < 2; ++e) {
                    float f0 = v[2 * e], f1 = v[2 * e + 1];
                    bool na0 = !(f0 == f0), na1 = !(f1 == f1);
                    unsigned int s0 = na0 ? 0u : (unsigned int)f2bf(f0);
                    unsigned int s1 = na1 ? 0u : (unsigned int)f2bf(f1);
                    unsigned int m0 = na0 ? 0x3F80u : 0u;
                    unsigned int m1 = na1 ? 0x3F80u : 0u;
                    wx[h * 2 + e] = s0 | (s1 << 16);
                    wm[h * 2 + e] = m0 | (m1 << 16);
                }
            }
            uint4v px = {wx[0], wx[1], wx[2], wx[3]};
            uint4v pm = {wm[0], wm[1], wm[2], wm[3]};
            *(uint4v*)&xs[ebase + ks * 512] = px;
            *(uint4v*)&mk[ebase + ks * 512] = pm;
        }
    }

    // ---- fused loglik + softmax via q-tables: 8 threads per row -> pws[row][3] ----
    {
        int row = tid >> 3;
        int sub = tid & 7;
        const floatx4* xr = (const floatx4*)(X + (size_t)(n0 + row) * P_DIM);
        const floatx4* qt = (const floatx4*)qtab;
        float a0 = 0.f, a1 = 0.f, a2 = 0.f;
#pragma unroll
        for (int i = 0; i < 8; ++i) {
            floatx4 v = xr[sub * 8 + i];
#pragma unroll
            for (int e = 0; e < 4; ++e) {
                float x = v[e];
                int p = sub * 32 + i * 4 + e;
                bool valid = (x == x);
                float xv = valid ? x : 0.f;
                floatx4 qa = qt[p * 3 + 0];
                floatx4 qb = qt[p * 3 + 1];
                floatx4 qd = qt[p * 3 + 2];
                float q0 = fmaf(fmaf(qa[0], xv, qb[0]), xv, qd[0]);
                float q1 = fmaf(fmaf(qa[1], xv, qb[1]), xv, qd[1]);
                float q2 = fmaf(fmaf(qa[2], xv, qb[2]), xv, qd[2]);
                a0 += valid ? q0 : 0.f;
                a1 += valid ? q1 : 0.f;
                a2 += valid ? q2 : 0.f;
            }
        }
#pragma unroll
        for (int off = 1; off < 8; off <<= 1) {
            a0 += __shfl_xor(a0, off);
            a1 += __shfl_xor(a1, off);
            a2 += __shfl_xor(a2, off);
        }
        if (sub == 0) {
            float z0 = logits[0] - a0;
            float z1 = logits[1] - a1;
            float z2 = logits[2] - a2;
            float mx = fmaxf(z0, fmaxf(z1, z2));
            float e0 = __expf(z0 - mx), e1 = __expf(z1 - mx), e2 = __expf(z2 - mx);
            float inv = __builtin_amdgcn_rcpf(e0 + e1 + e2);
            pws[row][0] = e0 * inv;
            pws[row][1] = e1 * inv;
            pws[row][2] = e2 * inv;
        }
    }
    __syncthreads();

    // ---- persistent u-loop: single-buffer packed-B k-loop + expected_relu epilogue ----
    const int wr   = wid >> 2;     // 0..1 : 32-row slab
    const int wc   = wid & 3;      // 0..3 : 16-col group
    // frag r (rows wr*32 + r*16 + l15): rowblk = wr*2 + r
    const int aBase = wr * 8192 + lk * 128 + l15 * 8;     // + r*4096 + ks*512
    const int phase = wc << 1;     // stagger: wc-groups at different u-phases

#pragma unroll 1
    for (int ut0 = 0; ut0 < NUT; ++ut0) {
        const int ut = (ut0 + phase) & (NUT - 1);
        // coalesced fragment base: Bf[ut][wc][.][.][lane][.]
        const unsigned short* bpw = Bf + ((size_t)(ut * 4 + wc) * (8 * 7 * 512)) + (size_t)lane * 8;

        f32x4 acc[NPLANES][2];
#pragma unroll
        for (int pl = 0; pl < NPLANES; ++pl)
#pragma unroll
            for (int r = 0; r < 2; ++r)
                acc[pl][r] = (f32x4){0.f, 0.f, 0.f, 0.f};

        short8 bR[NPLANES];
#pragma unroll 1
        for (int ks = 0; ks < 8; ++ks) {
            LOADB(bR, ks);                        // issue 7 coalesced 1KB loads
            __builtin_amdgcn_sched_barrier(0);    // keep loads above the MFMA cluster
            STEP(bR, ks);                         // 4 ds_reads + 14 MFMAs
        }

        // epilogue: D lane map col = lane&15, row = 4*(lane>>4)+q (+ r*16 + wr*32)
        const int ucol = ut * BU + wc * 16 + l15;
        const float bias_u = bias[ucol];
#pragma unroll
        for (int r = 0; r < 2; ++r) {
            int rloc = wr * 32 + r * 16 + 4 * lk;
#pragma unroll
            for (int q = 0; q < 4; ++q) {
                int rl = rloc + q;
                float p0 = pws[rl][0], p1 = pws[rl][1], p2 = pws[rl][2];
                float y0 = acc[0][r][q] + bias_u;
                float res = p0 * erl(y0 + acc[1][r][q], acc[4][r][q])
                          + p1 * erl(y0 + acc[2][r][q], acc[5][r][q])
                          + p2 * erl(y0 + acc[3][r][q], acc[6][r][q]);
                out[(size_t)(n0 + rl) * U_DIM + ucol] = res;
            }
        }
    }
}

extern "C" void kernel_launch(void* const* d_in, const int* in_sizes, int n_in,
                              void* d_out, int out_size, void* d_ws, size_t ws_size,
                              hipStream_t stream)
{
    const float* X      = (const float*)d_in[0];
    const float* cmeans = (const float*)d_in[1];
    const float* cvars  = (const float*)d_in[2];
    const float* logits = (const float*)d_in[3];
    const float* kern   = (const float*)d_in[4];
    const float* bias   = (const float*)d_in[5];
    float* out = (float*)d_out;

    char* wsb = (char*)d_ws;
    unsigned short* Bf = (unsigned short*)wsb;                 // 1,835,008 B
    float* qtab = (float*)(wsb + 1835008);                     //    12,288 B

    hipLaunchKernelGGL(prep_kernel, dim3(1794), dim3(512), 0, stream,
                       cmeans, cvars, kern, Bf, qtab);
    hipLaunchKernelGGL(main_kernel, dim3(N_ROWS / BM), dim3(512), 0, stream,
                       X, Bf, qtab, logits, bias, out);
}